// Round 1
// 357.751 us; speedup vs baseline: 1.3099x; 1.3099x over previous
//
#include <hip/hip_runtime.h>

typedef unsigned short u16;
typedef unsigned int u32;

#define B_ 4
#define S_ 2048
#define D_ 1024
#define H_ 16
#define HD_ 64
#define M_ (B_ * S_)    // 8192 rows
#define QK_ (2 * D_)    // 2048 (Q|K feature stride in qk ws)

typedef __bf16 bf16x8 __attribute__((ext_vector_type(8)));
typedef float f32x4 __attribute__((ext_vector_type(4)));

#define MASKVAL (-1.0e30f)

// hardware RNE f32->bf16 (single v_cvt, pairs get packed by the compiler)
static __device__ __forceinline__ u16 f2bf_hw(float f) {
    union { __bf16 b; u16 u; } v;
    v.b = (__bf16)f;
    return v.u;
}

// async global->LDS, 16B per lane. dst must be wave-uniform base; HW adds lane*16.
static __device__ __forceinline__ void gload16(const u16* g, u16* l) {
    __builtin_amdgcn_global_load_lds(
        (const __attribute__((address_space(1))) void*)g,
        (__attribute__((address_space(3))) void*)l, 16, 0, 0);
}

// ---------------- elementwise f32 -> bf16 convert (8 elems/thread) ----------
__global__ __launch_bounds__(256) void cvt_bf16(const float* __restrict__ src,
                                                u16* __restrict__ dst) {
    size_t i = ((size_t)blockIdx.x * 256 + threadIdx.x) * 8;
    float4 a = *(const float4*)(src + i);
    float4 b = *(const float4*)(src + i + 4);
    union { u16 h[8]; int4 v; } pk;
    pk.h[0] = f2bf_hw(a.x); pk.h[1] = f2bf_hw(a.y);
    pk.h[2] = f2bf_hw(a.z); pk.h[3] = f2bf_hw(a.w);
    pk.h[4] = f2bf_hw(b.x); pk.h[5] = f2bf_hw(b.y);
    pk.h[6] = f2bf_hw(b.z); pk.h[7] = f2bf_hw(b.w);
    *(int4*)(dst + i) = pk.v;
}

// ---------------- m97-structure bf16 GEMM: C[M,N] = A[M,K] * B[N,K]^T -------
// 128x128 tile, BK=64, 4 waves (2x2 of 64x64), global_load_lds staging,
// linear [128][64] LDS. EPI: 0 = bf16 C, 1 = transposed-Vt bf16, 2 = fp32 C.
template <int EPI>
__global__ __launch_bounds__(256) void gemm_bb(const u16* __restrict__ A,
                                               const u16* __restrict__ Bw,
                                               void* __restrict__ Cout,
                                               int Ndim, int Kdim) {
    __shared__ u16 Alds[128 * 64];
    __shared__ u16 Blds[128 * 64];
    const int t = threadIdx.x;
    const int bx = blockIdx.x, by = blockIdx.y;
    const int wave = t >> 6, lane = t & 63;
    const int ml = lane & 15, quad = lane >> 4;
    const int wm = (wave >> 1) * 64, wn = (wave & 1) * 64;
    const int rowA0 = by * 128, rowB0 = bx * 128;
    const int sr8 = lane >> 3;        // 0..7   staging row within 8-row slab
    const int sc8 = (lane & 7) * 8;   // 0..56  staging col (bf16 elems)

    f32x4 acc[4][4];
    const f32x4 zero = {0.f, 0.f, 0.f, 0.f};
#pragma unroll
    for (int i = 0; i < 4; ++i)
#pragma unroll
        for (int j = 0; j < 4; ++j) acc[i][j] = zero;

    for (int k0 = 0; k0 < Kdim; k0 += 64) {
        __syncthreads();
#pragma unroll
        for (int p = 0; p < 4; ++p) {
            const int rbase = wave * 32 + p * 8;   // wave-uniform slab base
            gload16(&A[(size_t)(rowA0 + rbase + sr8) * Kdim + k0 + sc8],
                    &Alds[rbase * 64]);
            gload16(&Bw[(size_t)(rowB0 + rbase + sr8) * Kdim + k0 + sc8],
                    &Blds[rbase * 64]);
        }
        __syncthreads();
#pragma unroll
        for (int kc = 0; kc < 2; ++kc) {
            bf16x8 a[4], b[4];
#pragma unroll
            for (int i = 0; i < 4; ++i)
                a[i] = *(const bf16x8*)(&Alds[(wm + i * 16 + ml) * 64 + kc * 32 + quad * 8]);
#pragma unroll
            for (int j = 0; j < 4; ++j)
                b[j] = *(const bf16x8*)(&Blds[(wn + j * 16 + ml) * 64 + kc * 32 + quad * 8]);
#pragma unroll
            for (int i = 0; i < 4; ++i)
#pragma unroll
                for (int j = 0; j < 4; ++j)
                    acc[i][j] = __builtin_amdgcn_mfma_f32_16x16x32_bf16(a[i], b[j], acc[i][j], 0, 0, 0);
        }
    }

    if constexpr (EPI == 0) {
        u16* C = (u16*)Cout;
#pragma unroll
        for (int i = 0; i < 4; ++i)
#pragma unroll
            for (int j = 0; j < 4; ++j)
#pragma unroll
                for (int r = 0; r < 4; ++r) {
                    int row = rowA0 + wm + i * 16 + quad * 4 + r;
                    int col = rowB0 + wn + j * 16 + ml;
                    C[(size_t)row * Ndim + col] = f2bf_hw(acc[i][j][r]);
                }
    } else if constexpr (EPI == 1) {
        u16* Vt = (u16*)Cout;
#pragma unroll
        for (int i = 0; i < 4; ++i)
#pragma unroll
            for (int j = 0; j < 4; ++j) {
                int row0 = rowA0 + wm + i * 16 + quad * 4;  // token, multiple of 4
                int col = rowB0 + wn + j * 16 + ml;         // V feature
                int b = row0 >> 11;
                int s0 = row0 & (S_ - 1);
                union { u16 h[4]; ushort4 v; } pk;
#pragma unroll
                for (int r = 0; r < 4; ++r) pk.h[r] = f2bf_hw(acc[i][j][r]);
                *(ushort4*)(&Vt[((size_t)(b * D_ + col)) * S_ + s0]) = pk.v;
            }
    } else {
        float* C = (float*)Cout;
#pragma unroll
        for (int i = 0; i < 4; ++i)
#pragma unroll
            for (int j = 0; j < 4; ++j)
#pragma unroll
                for (int r = 0; r < 4; ++r) {
                    int row = rowA0 + wm + i * 16 + quad * 4 + r;
                    int col = rowB0 + wn + j * 16 + ml;
                    C[(size_t)row * Ndim + col] = acc[i][j][r];
                }
    }
}

// attn2: uniform-work flash attention (unchanged structure; hw bf16 cvt).
__global__ __launch_bounds__(256, 2) void attn2(const u16* __restrict__ qk,
                                                const u16* __restrict__ Vt,
                                                u16* __restrict__ AO) {
    __shared__ u16 Klds[64][68];
    __shared__ u16 Vlds[64][68];
    __shared__ u16 Plds[4][32 * 68];
    const int t = threadIdx.x;
    const int wave = t >> 6, lane = t & 63;
    const int ml = lane & 15, quad = lane >> 4;
    const int j = blockIdx.x >> 6;       // 0..7
    const int bh = blockIdx.x & 63;      // head id
    const int b = bh >> 4, h = bh & 15;
    const size_t rowbase = (size_t)b * S_;
    const int sr = t >> 3, sseg = (t & 7) * 8;

    int qw[2], ktw[2];
    qw[0] = j * 128 + wave * 32;
    qw[1] = (15 - j) * 128 + wave * 32;
    ktw[0] = (qw[0] + 31) >> 6;
    ktw[1] = (qw[1] + 31) >> 6;
    const int ktmax = ((15 - j) * 128 + 127) >> 6;

    bf16x8 qf[2][2][2];
#pragma unroll
    for (int T = 0; T < 2; ++T)
#pragma unroll
        for (int mi = 0; mi < 2; ++mi)
#pragma unroll
            for (int kc = 0; kc < 2; ++kc)
                qf[T][mi][kc] = *(const bf16x8*)(&qk[(rowbase + qw[T] + mi * 16 + ml) * QK_ +
                                                     h * HD_ + kc * 32 + quad * 8]);

    f32x4 o[2][2][4];
    float m[2][2][4], ls[2][2][4];
    const f32x4 zero = {0.f, 0.f, 0.f, 0.f};
#pragma unroll
    for (int T = 0; T < 2; ++T)
#pragma unroll
        for (int mi = 0; mi < 2; ++mi) {
#pragma unroll
            for (int nd = 0; nd < 4; ++nd) o[T][mi][nd] = zero;
#pragma unroll
            for (int r = 0; r < 4; ++r) { m[T][mi][r] = MASKVAL; ls[T][mi][r] = 0.f; }
        }

    for (int kt = 0; kt <= ktmax; ++kt) {
        const int kb = kt * 64;
        __syncthreads();
#pragma unroll
        for (int p = 0; p < 2; ++p) {
            int r = sr + p * 32;
            *(int4*)(&Klds[r][sseg]) =
                *(const int4*)(&qk[(rowbase + kb + r) * QK_ + D_ + h * HD_ + sseg]);
            *(int4*)(&Vlds[r][sseg]) =
                *(const int4*)(&Vt[(size_t)(bh * HD_ + r) * S_ + kb + sseg]);
        }
        __syncthreads();
        if (kt > ktw[1]) continue;

        bf16x8 kf[4][2], vf[4][2];
#pragma unroll
        for (int ni = 0; ni < 4; ++ni)
#pragma unroll
            for (int kc = 0; kc < 2; ++kc) {
                kf[ni][kc] = *(const bf16x8*)(&Klds[ni * 16 + ml][kc * 32 + quad * 8]);
                vf[ni][kc] = *(const bf16x8*)(&Vlds[ni * 16 + ml][kc * 32 + quad * 8]);
            }

#pragma unroll
        for (int T = 0; T < 2; ++T) {
            if (kt > ktw[T]) continue;
            const int qT = qw[T];
            f32x4 sc[2][4];
#pragma unroll
            for (int mi = 0; mi < 2; ++mi)
#pragma unroll
                for (int ni = 0; ni < 4; ++ni) {
                    f32x4 s = zero;
#pragma unroll
                    for (int kc = 0; kc < 2; ++kc)
                        s = __builtin_amdgcn_mfma_f32_16x16x32_bf16(qf[T][mi][kc], kf[ni][kc], s, 0, 0, 0);
                    sc[mi][ni] = s;
                }
            if (kb + 63 <= qT) {
#pragma unroll
                for (int mi = 0; mi < 2; ++mi)
#pragma unroll
                    for (int ni = 0; ni < 4; ++ni)
#pragma unroll
                        for (int r = 0; r < 4; ++r) sc[mi][ni][r] *= 0.125f;
            } else {
#pragma unroll
                for (int mi = 0; mi < 2; ++mi)
#pragma unroll
                    for (int ni = 0; ni < 4; ++ni)
#pragma unroll
                        for (int r = 0; r < 4; ++r) {
                            int q = qT + mi * 16 + quad * 4 + r;
                            int k = kb + ni * 16 + ml;
                            float v = sc[mi][ni][r] * 0.125f;
                            sc[mi][ni][r] = (k > q) ? MASKVAL : v;
                        }
            }
#pragma unroll
            for (int mi = 0; mi < 2; ++mi) {
                float tm[4], al[4];
#pragma unroll
                for (int r = 0; r < 4; ++r)
                    tm[r] = fmaxf(fmaxf(sc[mi][0][r], sc[mi][1][r]),
                                  fmaxf(sc[mi][2][r], sc[mi][3][r]));
#pragma unroll
                for (int off = 1; off <= 8; off <<= 1)
#pragma unroll
                    for (int r = 0; r < 4; ++r)
                        tm[r] = fmaxf(tm[r], __shfl_xor(tm[r], off, 64));
#pragma unroll
                for (int r = 0; r < 4; ++r) {
                    float mn = fmaxf(m[T][mi][r], tm[r]);
                    al[r] = __expf(m[T][mi][r] - mn);
                    m[T][mi][r] = mn;
                }
#pragma unroll
                for (int ni = 0; ni < 4; ++ni)
#pragma unroll
                    for (int r = 0; r < 4; ++r)
                        sc[mi][ni][r] = __expf(sc[mi][ni][r] - m[T][mi][r]);
#pragma unroll
                for (int r = 0; r < 4; ++r)
                    ls[T][mi][r] = ls[T][mi][r] * al[r] +
                                   ((sc[mi][0][r] + sc[mi][1][r]) + (sc[mi][2][r] + sc[mi][3][r]));
#pragma unroll
                for (int nd = 0; nd < 4; ++nd)
#pragma unroll
                    for (int r = 0; r < 4; ++r) o[T][mi][nd][r] *= al[r];
#pragma unroll
                for (int ni = 0; ni < 4; ++ni)
#pragma unroll
                    for (int r = 0; r < 4; ++r)
                        Plds[wave][(mi * 16 + quad * 4 + r) * 68 + ni * 16 + ml] = f2bf_hw(sc[mi][ni][r]);
            }
            asm volatile("s_waitcnt lgkmcnt(0)" ::: "memory");
            bf16x8 pf[2][2];
#pragma unroll
            for (int mi = 0; mi < 2; ++mi)
#pragma unroll
                for (int kc = 0; kc < 2; ++kc)
                    pf[mi][kc] = *(const bf16x8*)(&Plds[wave][(mi * 16 + ml) * 68 + kc * 32 + quad * 8]);
#pragma unroll
            for (int mi = 0; mi < 2; ++mi)
#pragma unroll
                for (int nd = 0; nd < 4; ++nd)
#pragma unroll
                    for (int kc = 0; kc < 2; ++kc)
                        o[T][mi][nd] = __builtin_amdgcn_mfma_f32_16x16x32_bf16(pf[mi][kc], vf[nd][kc],
                                                                               o[T][mi][nd], 0, 0, 0);
        }
    }
#pragma unroll
    for (int T = 0; T < 2; ++T)
#pragma unroll
        for (int mi = 0; mi < 2; ++mi) {
            float s4[4], rl[4];
#pragma unroll
            for (int r = 0; r < 4; ++r) s4[r] = ls[T][mi][r];
#pragma unroll
            for (int off = 1; off <= 8; off <<= 1)
#pragma unroll
                for (int r = 0; r < 4; ++r) s4[r] += __shfl_xor(s4[r], off, 64);
#pragma unroll
            for (int r = 0; r < 4; ++r) rl[r] = 1.0f / s4[r];
#pragma unroll
            for (int nd = 0; nd < 4; ++nd)
#pragma unroll
                for (int r = 0; r < 4; ++r) {
                    int srow = qw[T] + mi * 16 + quad * 4 + r;
                    AO[(rowbase + srow) * D_ + h * HD_ + nd * 16 + ml] =
                        f2bf_hw(o[T][mi][nd][r] * rl[r]);
                }
        }
}

// 16B-per-thread d2d copy
__global__ __launch_bounds__(256) void copy16(const int4* __restrict__ src,
                                              int4* __restrict__ dst) {
    size_t i = (size_t)blockIdx.x * 256 + threadIdx.x;
    dst[i] = src[i];
}

extern "C" void kernel_launch(void* const* d_in, const int* in_sizes, int n_in,
                              void* d_out, int out_size, void* d_ws, size_t ws_size,
                              hipStream_t stream) {
    const float* x = (const float*)d_in[0];      // [B,S,D] f32
    const float* wqkv = (const float*)d_in[1];   // [3D,D] f32
    const float* wproj = (const float*)d_in[2];  // [D,D] f32
    float* out = (float*)d_out;                  // [B,S,D] fp32

    // workspace: qk [M,2D] bf16 (33.55 MB) + Vt [B*H*HD, S] bf16 (16.78 MB)
    u16* qkw = (u16*)d_ws;
    u16* Vtw = qkw + (size_t)M_ * QK_;

    // d_out doubles as bf16 scratch until the final projection:
    //   [0      , 8M)  xb      (x in bf16)      -- dead after gemm_vt, becomes AO
    //   [8M     , 9M)  wprojb  (w_proj bf16)
    //   [9M     , 12M) wqkvb   (w_qkv bf16)
    u16* xb = (u16*)d_out;
    u16* wprojb = xb + (size_t)M_ * D_;
    u16* wqkvb = wprojb + (size_t)D_ * D_;
    u16* AOtmp = xb;                   // attn output overwrites xb region
    u16* AOws = qkw;                   // qk region reused after attn
    u16* wprojws = qkw + (size_t)M_ * D_;

    // f32 -> bf16 converts (one-time)
    cvt_bf16<<<dim3(M_ * D_ / 2048), 256, 0, stream>>>(x, xb);
    cvt_bf16<<<dim3(D_ * D_ / 2048), 256, 0, stream>>>(wproj, wprojb);
    cvt_bf16<<<dim3(3 * D_ * D_ / 2048), 256, 0, stream>>>(wqkv, wqkvb);

    // QK projection: [M,2D] bf16
    gemm_bb<0><<<dim3(QK_ / 128, M_ / 128), 256, 0, stream>>>(xb, wqkvb, qkw, QK_, D_);
    // V projection with transposed epilogue
    gemm_bb<1><<<dim3(D_ / 128, M_ / 128), 256, 0, stream>>>(
        xb, wqkvb + (size_t)QK_ * D_, Vtw, D_, D_);
    // attention
    attn2<<<dim3(512), 256, 0, stream>>>(qkw, Vtw, AOtmp);
    // move AO + wprojb (contiguous 9M u16) out of d_out before proj writes it
    copy16<<<dim3((unsigned)(((size_t)M_ * D_ + (size_t)D_ * D_) * 2 / (256 * 16))),
             256, 0, stream>>>((const int4*)AOtmp, (int4*)AOws);
    // output projection: fp32 out
    gemm_bb<2><<<dim3(D_ / 128, M_ / 128), 256, 0, stream>>>(AOws, wprojws, out, D_, D_);
}